// Round 4
// baseline (206.731 us; speedup 1.0000x reference)
//
#include <hip/hip_runtime.h>

#define NROWS 131072
#define NCLS  1000
#define CPAD  1024
#define DDIM  256

typedef __attribute__((ext_vector_type(8))) short bf16x8;
typedef __attribute__((ext_vector_type(4))) float f32x4;

__device__ __forceinline__ float wred(float v){
#pragma unroll
  for (int m = 1; m < 64; m <<= 1) v += __shfl_xor(v, m, 64);
  return v;
}

__device__ __forceinline__ ushort f2bf(float x){
  union { float f; unsigned u; } c; c.f = x;
  return (ushort)((c.u + 0x7FFFu + ((c.u >> 16) & 1u)) >> 16);
}

// ---------------------------------------------------------------------------
// Kernel 1: 4 classes per block, 1024 threads (16 waves). Each wave ballot-
// scans a disjoint 8192-row label slice (int4 loads), gathers matching rows
// coalesced, then batch_center -> update_wei -> new_memory runs in-block
// (wave c of 0..3 finishes class c0+c). Deterministic order throughout.
// ---------------------------------------------------------------------------
__global__ __launch_bounds__(1024) void k_center(
    const float* __restrict__ feat, const float* __restrict__ memory,
    const int* __restrict__ label, ushort* __restrict__ nmem){
  const int c0 = blockIdx.x * 4;
  const int t = threadIdx.x;
  const int w = t >> 6, lane = t & 63;
  if (c0 >= NCLS){                 // zero pad rows -> padded logits exactly 0
    if (t < 256) ((ushort4*)nmem)[c0*64 + t] = make_ushort4(0,0,0,0);
    return;
  }
  __shared__ float4 accred[4][16][64];   // 64 KB
  __shared__ int cw[4][16];

  float4 a[4];
  int cnt[4];
#pragma unroll
  for (int cc = 0; cc < 4; ++cc){ a[cc] = make_float4(0.f,0.f,0.f,0.f); cnt[cc] = 0; }
  const float4* feat4 = (const float4*)feat;
  const int4*   lab4  = (const int4*)label;

  for (int it = 0; it < 32; ++it){
    int base = (w*32 + it) * 256;            // wave w owns rows [w*8192, +8192)
    int4 lv = lab4[base/4 + lane];
#pragma unroll
    for (int sub = 0; sub < 4; ++sub){
      int lvv = (sub==0)?lv.x:(sub==1)?lv.y:(sub==2)?lv.z:lv.w;
#pragma unroll
      for (int cc = 0; cc < 4; ++cc){
        unsigned long long m = __ballot(lvv == c0 + cc);
        cnt[cc] += (int)__popcll(m);
        while (m){
          int b = __ffsll((long long)m) - 1; m &= m - 1;
          int r = base + b*4 + sub;
          float4 x = feat4[r*64 + lane];
          float ss = wred(x.x*x.x + x.y*x.y + x.z*x.z + x.w*x.w);
          float sc = 1.0f / fmaxf(sqrtf(ss), 1e-12f);
          a[cc].x += x.x*sc; a[cc].y += x.y*sc; a[cc].z += x.z*sc; a[cc].w += x.w*sc;
        }
      }
    }
  }
#pragma unroll
  for (int cc = 0; cc < 4; ++cc) accred[cc][w][lane] = a[cc];
  if (lane == 0){
#pragma unroll
    for (int cc = 0; cc < 4; ++cc) cw[cc][w] = cnt[cc];
  }
  __syncthreads();

  if (t < 256){                     // wave cls finishes class c0+cls
    int cls = t >> 6, ln = t & 63;
    float sx=0.f, sy=0.f, sz=0.f, sw=0.f; int total = 0;
#pragma unroll
    for (int s = 0; s < 16; ++s){
      float4 v = accred[cls][s][ln];
      sx += v.x; sy += v.y; sz += v.z; sw += v.w;
      total += cw[cls][s];
    }
    int c = c0 + cls;
    float ss = wred(sx*sx + sy*sy + sz*sz + sw*sw);
    float inv = 1.0f / fmaxf(sqrtf(ss), 1e-12f);
    float bx = sx*inv, by = sy*inv, bz = sz*inv, bw = sw*inv;  // 0 if empty
    float flag = (total > 0) ? 1.0f : 0.0f;
    float4 m = ((const float4*)memory)[c*64 + ln];
    float simi = wred(m.x*bx + m.y*by + m.z*bz + m.w*bw);
    float wei = 1.0f - (1.0f - simi)*flag;
    float rx = wei*m.x + (1.0f-wei)*bx;
    float ry = wei*m.y + (1.0f-wei)*by;
    float rz = wei*m.z + (1.0f-wei)*bz;
    float rw = wei*m.w + (1.0f-wei)*bw;
    float ss2 = wred(rx*rx + ry*ry + rz*rz + rw*rw);
    float inv2 = 1.0f / fmaxf(sqrtf(ss2), 1e-12f);
    ((ushort4*)nmem)[c*64 + ln] =
        make_ushort4(f2bf(rx*inv2), f2bf(ry*inv2), f2bf(rz*inv2), f2bf(rw*inv2));
  }
}

// ---------------------------------------------------------------------------
// Kernel 2: fused GEMM + softmax-denominator + label-logit.
//  8-wave (512-thread) blocks, 256 rows/block, 32 rows/wave -> 16 waves/CU
//  (4/SIMD) at 2 blocks/CU for latency hiding. A in VGPRs (fragment layout,
//  unnormalized bf16; 1/||a|| folded into epilogue). B chunk double-buffered
//  in LDS, FRAGMENT-LINEAR (frag p=k*4+nb at [p*1024 + lane*16)): staged via
//  global_load_lds(16B) with per-lane pre-permuted GLOBAL source and linear
//  wave-uniform LDS dest -> zero bank conflicts. Wave w stages its k-slice
//  (4 frags). Pipeline: STAGE(ch+1) -> compute(ch) -> vmcnt(0) -> barrier.
//  Padded cols are exact zeros -> each contributes exp(0)=1: subtract 24.
// ---------------------------------------------------------------------------
__global__ __launch_bounds__(512, 4) void k_gemm(
    const float* __restrict__ feat, const ushort* __restrict__ nmem,
    const int* __restrict__ label, float* __restrict__ partials){
  __shared__ alignas(16) char Bl[2*32768];   // 64 KB: 2 bufs x 32 frags x 1KB
  __shared__ float rowinv[256];
  __shared__ float bred[8];
  const int t = threadIdx.x, w = t >> 6, lane = t & 63;
  const int g = lane >> 4, r16 = lane & 15;
  const int rowbase = blockIdx.x * 256;

  // ---- A: global -> registers in fragment layout; row sumsq on the fly
  bf16x8 areg[2][8];
  float rs_self[2];
#pragma unroll
  for (int mf = 0; mf < 2; ++mf){
    int row = rowbase + w*32 + mf*16 + r16;
    const float4* rp = (const float4*)(feat + row*DDIM);
    float ss = 0.f;
#pragma unroll
    for (int kt = 0; kt < 8; ++kt){
      float4 x0 = rp[kt*8 + g*2];
      float4 x1 = rp[kt*8 + g*2 + 1];
      ss += x0.x*x0.x + x0.y*x0.y + x0.z*x0.z + x0.w*x0.w
          + x1.x*x1.x + x1.y*x1.y + x1.z*x1.z + x1.w*x1.w;
      bf16x8 pk;
      pk[0]=(short)f2bf(x0.x); pk[1]=(short)f2bf(x0.y);
      pk[2]=(short)f2bf(x0.z); pk[3]=(short)f2bf(x0.w);
      pk[4]=(short)f2bf(x1.x); pk[5]=(short)f2bf(x1.y);
      pk[6]=(short)f2bf(x1.z); pk[7]=(short)f2bf(x1.w);
      areg[mf][kt] = pk;
    }
    ss += __shfl_xor(ss, 16, 64);    // lanes l, l^16, l^32, l^48 share a row
    ss += __shfl_xor(ss, 32, 64);
    rs_self[mf] = 1.0f / fmaxf(sqrtf(ss), 1e-12f);
  }
  if (lane < 16){                    // wave-local publish/read: no barrier
    rowinv[w*32 + lane]      = rs_self[0];
    rowinv[w*32 + 16 + lane] = rs_self[1];
  }

  int labreg[2][4];
  float rs[2][4];
#pragma unroll
  for (int m = 0; m < 2; ++m)
#pragma unroll
    for (int j = 0; j < 4; ++j){
      int rr = w*32 + m*16 + g*4 + j;       // C-frag row of acc[m][*][j]
      labreg[m][j] = label[rowbase + rr];
      rs[m][j] = rowinv[rr];
    }

  // ---- staging: wave w owns frags p = w*4+nb (its k-slice k=w, nb=0..3).
  // frag(k,nb) lane l = nmem[ch*64 + nb*16 + r16] bytes [k*64+g*16, +16)
  const char* sbase = (const char*)nmem + (size_t)(r16*512 + w*64 + g*16);
  char* dbase = (char*)Bl + w*4096;

#define STAGE(CH, BUF)                                                        \
  {                                                                           \
    const char* s0 = sbase + (CH)*32768;                                      \
    char* d0 = dbase + (BUF)*32768;                                           \
    _Pragma("unroll")                                                         \
    for (int i = 0; i < 4; ++i){                                              \
      __builtin_amdgcn_global_load_lds(                                       \
        (const __attribute__((address_space(1))) unsigned*)(s0 + i*8192),     \
        (__attribute__((address_space(3))) unsigned*)(d0 + i*1024), 16, 0, 0);\
    }                                                                         \
  }

  STAGE(0, 0);
  asm volatile("s_waitcnt vmcnt(0)" ::: "memory");   // drains A-loads + stage0
  __builtin_amdgcn_s_barrier();

  float esum[2][4] = {{0.f,0.f,0.f,0.f},{0.f,0.f,0.f,0.f}};
  float slb [2][4] = {{0.f,0.f,0.f,0.f},{0.f,0.f,0.f,0.f}};

  for (int ch = 0; ch < 16; ++ch){
    if (ch < 15) STAGE(ch+1, (ch+1)&1);     // in flight across the compute

    const char* bp = (const char*)Bl + (ch&1)*32768 + lane*16;
    f32x4 acc[2][4];
#pragma unroll
    for (int m = 0; m < 2; ++m)
#pragma unroll
      for (int n = 0; n < 4; ++n){ f32x4 z = {0.f,0.f,0.f,0.f}; acc[m][n] = z; }

#pragma unroll
    for (int k = 0; k < 8; ++k){
      bf16x8 b0 = *(const bf16x8*)(bp + (k*4+0)*1024);
      bf16x8 b1 = *(const bf16x8*)(bp + (k*4+1)*1024);
      bf16x8 b2 = *(const bf16x8*)(bp + (k*4+2)*1024);
      bf16x8 b3 = *(const bf16x8*)(bp + (k*4+3)*1024);
      acc[0][0] = __builtin_amdgcn_mfma_f32_16x16x32_bf16(areg[0][k], b0, acc[0][0], 0, 0, 0);
      acc[0][1] = __builtin_amdgcn_mfma_f32_16x16x32_bf16(areg[0][k], b1, acc[0][1], 0, 0, 0);
      acc[0][2] = __builtin_amdgcn_mfma_f32_16x16x32_bf16(areg[0][k], b2, acc[0][2], 0, 0, 0);
      acc[0][3] = __builtin_amdgcn_mfma_f32_16x16x32_bf16(areg[0][k], b3, acc[0][3], 0, 0, 0);
      acc[1][0] = __builtin_amdgcn_mfma_f32_16x16x32_bf16(areg[1][k], b0, acc[1][0], 0, 0, 0);
      acc[1][1] = __builtin_amdgcn_mfma_f32_16x16x32_bf16(areg[1][k], b1, acc[1][1], 0, 0, 0);
      acc[1][2] = __builtin_amdgcn_mfma_f32_16x16x32_bf16(areg[1][k], b2, acc[1][2], 0, 0, 0);
      acc[1][3] = __builtin_amdgcn_mfma_f32_16x16x32_bf16(areg[1][k], b3, acc[1][3], 0, 0, 0);
    }

    // ---- epilogue: scale by row inv-norm, exp-accumulate, label select
#pragma unroll
    for (int m = 0; m < 2; ++m)
#pragma unroll
      for (int n = 0; n < 4; ++n){
        int col = ch*64 + n*16 + r16;
#pragma unroll
        for (int j = 0; j < 4; ++j){
          float v = acc[m][n][j] * rs[m][j];
          esum[m][j] += __expf(v);
          slb[m][j]  += (col == labreg[m][j]) ? v : 0.f;
        }
      }

    asm volatile("s_waitcnt vmcnt(0)" ::: "memory");  // next buf landed
    __builtin_amdgcn_s_barrier();                     // all waves past reads
  }

  // ---- final: reduce 16-lane groups once, per-block loss partial
  float v = 0.f;
#pragma unroll
  for (int m = 0; m < 2; ++m)
#pragma unroll
    for (int j = 0; j < 4; ++j){
      float e = esum[m][j], s = slb[m][j];
      e += __shfl_xor(e, 1, 64); e += __shfl_xor(e, 2, 64);
      e += __shfl_xor(e, 4, 64); e += __shfl_xor(e, 8, 64);
      s += __shfl_xor(s, 1, 64); s += __shfl_xor(s, 2, 64);
      s += __shfl_xor(s, 4, 64); s += __shfl_xor(s, 8, 64);
      v += __logf(e - 24.0f) - s;      // 24 padded cols contribute exp(0)=1
    }
  if (r16 != 0) v = 0.f;               // one lane per 16-lane row-group
  v = wred(v);
  if (lane == 0) bred[w] = v;
  __syncthreads();
  if (t == 0){
    float s = 0.f;
#pragma unroll
    for (int i = 0; i < 8; ++i) s += bred[i];
    partials[blockIdx.x] = s;
  }
}

// ---------------------------------------------------------------------------
// Kernel 3: reduce 512 block partials -> mean loss (deterministic order)
// ---------------------------------------------------------------------------
__global__ __launch_bounds__(256) void k_final(
    const float* __restrict__ partials, float* __restrict__ out){
  const int t = threadIdx.x;
  const int w = t >> 6, lane = t & 63;
  __shared__ float red[4];
  float s = partials[t] + partials[t+256];
  s = wred(s);
  if (lane == 0) red[w] = s;
  __syncthreads();
  if (t == 0) out[0] = (red[0]+red[1]+red[2]+red[3]) * (1.0f/(float)NROWS);
}

// ---------------------------------------------------------------------------
// ws layout: [0, 524288) new_memory bf16 bits (1024x256), [524288, +2048) partials
// ---------------------------------------------------------------------------
extern "C" void kernel_launch(void* const* d_in, const int* in_sizes, int n_in,
                              void* d_out, int out_size, void* d_ws, size_t ws_size,
                              hipStream_t stream){
  const float* feat   = (const float*)d_in[0];
  const float* memory = (const float*)d_in[1];
  const int*   label  = (const int*)d_in[2];
  float* out = (float*)d_out;
  ushort* nmem = (ushort*)d_ws;
  float* partials = (float*)((char*)d_ws + (size_t)CPAD*DDIM*2);

  k_center<<<CPAD/4, 1024, 0, stream>>>(feat, memory, label, nmem);
  k_gemm<<<NROWS/256, 512, 0, stream>>>(feat, nmem, label, partials);
  k_final<<<1, 256, 0, stream>>>(partials, out);
}

// Round 5
// 144.751 us; speedup vs baseline: 1.4282x; 1.4282x over previous
//
#include <hip/hip_runtime.h>

#define NROWS 131072
#define NCLS  1000
#define CPAD  1024
#define DDIM  256

typedef __attribute__((ext_vector_type(8))) short bf16x8;
typedef __attribute__((ext_vector_type(4))) float f32x4;

__device__ __forceinline__ float wred(float v){
#pragma unroll
  for (int m = 1; m < 64; m <<= 1) v += __shfl_xor(v, m, 64);
  return v;
}

__device__ __forceinline__ ushort f2bf(float x){
  union { float f; unsigned u; } c; c.f = x;
  return (ushort)((c.u + 0x7FFFu + ((c.u >> 16) & 1u)) >> 16);
}

// ---------------------------------------------------------------------------
// Kernel 1: 2 classes per block, 1024 threads (16 waves). Ballot-scan labels
// (int4 loads), gather matching rows coalesced, then the full
// batch_center -> update_wei -> new_memory chain in-block. Deterministic.
// (R3 version — measured ~22us envelope, near the 134MB feat-read floor.)
// ---------------------------------------------------------------------------
__global__ __launch_bounds__(1024) void k_center(
    const float* __restrict__ feat, const float* __restrict__ memory,
    const int* __restrict__ label, ushort* __restrict__ nmem){
  const int c0 = blockIdx.x * 2;
  const int t = threadIdx.x;
  const int w = t >> 6, lane = t & 63;
  if (c0 >= NCLS){                 // zero pad rows -> padded logits exactly 0
    if (t < 128) ((ushort4*)nmem)[c0*64 + t] = make_ushort4(0,0,0,0);
    return;
  }
  const int c1 = c0 + 1;
  __shared__ float4 accred[2][16][64];
  __shared__ int cw[2][16];

  float4 a0 = make_float4(0.f,0.f,0.f,0.f);
  float4 a1 = make_float4(0.f,0.f,0.f,0.f);
  int cnt0 = 0, cnt1 = 0;
  const float4* feat4 = (const float4*)feat;
  const int4*   lab4  = (const int4*)label;

  for (int it = 0; it < 32; ++it){
    int base = (w*32 + it) * 256;              // wave w owns rows [w*8192, +8192)
    int4 lv = lab4[base/4 + lane];
#pragma unroll
    for (int sub = 0; sub < 4; ++sub){
      int lvv = (sub==0)?lv.x:(sub==1)?lv.y:(sub==2)?lv.z:lv.w;
      unsigned long long m0 = __ballot(lvv == c0);
      unsigned long long m1 = __ballot(lvv == c1);
      cnt0 += (int)__popcll(m0); cnt1 += (int)__popcll(m1);
      while (m0){
        int b = __ffsll((long long)m0) - 1; m0 &= m0 - 1;
        int r = base + b*4 + sub;
        float4 x = feat4[r*64 + lane];
        float ss = wred(x.x*x.x + x.y*x.y + x.z*x.z + x.w*x.w);
        float sc = 1.0f / fmaxf(sqrtf(ss), 1e-12f);
        a0.x += x.x*sc; a0.y += x.y*sc; a0.z += x.z*sc; a0.w += x.w*sc;
      }
      while (m1){
        int b = __ffsll((long long)m1) - 1; m1 &= m1 - 1;
        int r = base + b*4 + sub;
        float4 x = feat4[r*64 + lane];
        float ss = wred(x.x*x.x + x.y*x.y + x.z*x.z + x.w*x.w);
        float sc = 1.0f / fmaxf(sqrtf(ss), 1e-12f);
        a1.x += x.x*sc; a1.y += x.y*sc; a1.z += x.z*sc; a1.w += x.w*sc;
      }
    }
  }
  accred[0][w][lane] = a0; accred[1][w][lane] = a1;
  if (lane == 0){ cw[0][w] = cnt0; cw[1][w] = cnt1; }
  __syncthreads();

  if (t < 128){                     // wave 0 -> c0, wave 1 -> c1
    int cls = t >> 6, ln = t & 63;
    float sx=0.f, sy=0.f, sz=0.f, sw=0.f; int total = 0;
#pragma unroll
    for (int s = 0; s < 16; ++s){
      float4 v = accred[cls][s][ln];
      sx += v.x; sy += v.y; sz += v.z; sw += v.w;
      total += cw[cls][s];
    }
    int c = c0 + cls;
    float ss = wred(sx*sx + sy*sy + sz*sz + sw*sw);
    float inv = 1.0f / fmaxf(sqrtf(ss), 1e-12f);
    float bx = sx*inv, by = sy*inv, bz = sz*inv, bw = sw*inv;  // 0 if empty
    float flag = (total > 0) ? 1.0f : 0.0f;
    float4 m = ((const float4*)memory)[c*64 + ln];
    float simi = wred(m.x*bx + m.y*by + m.z*bz + m.w*bw);
    float wei = 1.0f - (1.0f - simi)*flag;
    float rx = wei*m.x + (1.0f-wei)*bx;
    float ry = wei*m.y + (1.0f-wei)*by;
    float rz = wei*m.z + (1.0f-wei)*bz;
    float rw = wei*m.w + (1.0f-wei)*bw;
    float ss2 = wred(rx*rx + ry*ry + rz*rz + rw*rw);
    float inv2 = 1.0f / fmaxf(sqrtf(ss2), 1e-12f);
    ((ushort4*)nmem)[c*64 + ln] =
        make_ushort4(f2bf(rx*inv2), f2bf(ry*inv2), f2bf(rz*inv2), f2bf(rw*inv2));
  }
}

// ---------------------------------------------------------------------------
// Kernel 2: fused GEMM + softmax-denominator + label-logit.
//  8-wave (512-thread) blocks, 256 rows/block, 32 rows/wave. A in VGPRs
//  (fragment layout, unnormalized bf16; 1/||a|| folded into epilogue logits).
//  B chunk double-buffered in LDS, FRAGMENT-LINEAR: staged via
//  global_load_lds(16B) with per-lane pre-permuted GLOBAL source and linear
//  wave-uniform LDS dest -> zero bank conflicts, ds_reads are base+lane*16
//  with immediate offsets. Wave w stages its k-slice (4 frags/chunk).
//  Pipeline: STAGE(ch+1) -> compute(ch) -> vmcnt(0) -> barrier.
//  Padded cols (1000..1023) are exact zeros -> exp(0)=1 each: subtract 24.
//  launch_bounds (512,2): cap >=128 VGPR so the natural ~124-reg allocation
//  survives (R4's (512,4) capped to 64 and spilled 233MB to scratch);
//  runtime occupancy from actual VGPR count: 124<=128 -> 4 waves/SIMD.
// ---------------------------------------------------------------------------
__global__ __launch_bounds__(512, 2) void k_gemm(
    const float* __restrict__ feat, const ushort* __restrict__ nmem,
    const int* __restrict__ label, float* __restrict__ partials){
  __shared__ alignas(16) char Bl[2*32768];   // 64 KB: 2 bufs x 32 frags x 1KB
  __shared__ float rowinv[256];
  __shared__ float bred[8];
  const int t = threadIdx.x, w = t >> 6, lane = t & 63;
  const int g = lane >> 4, r16 = lane & 15;
  const int rowbase = blockIdx.x * 256;

  // ---- A: global -> registers in fragment layout; row sumsq on the fly
  bf16x8 areg[2][8];
  float rs_self[2];
#pragma unroll
  for (int mf = 0; mf < 2; ++mf){
    int row = rowbase + w*32 + mf*16 + r16;
    const float4* rp = (const float4*)(feat + row*DDIM);
    float ss = 0.f;
#pragma unroll
    for (int kt = 0; kt < 8; ++kt){
      float4 x0 = rp[kt*8 + g*2];
      float4 x1 = rp[kt*8 + g*2 + 1];
      ss += x0.x*x0.x + x0.y*x0.y + x0.z*x0.z + x0.w*x0.w
          + x1.x*x1.x + x1.y*x1.y + x1.z*x1.z + x1.w*x1.w;
      bf16x8 pk;
      pk[0]=(short)f2bf(x0.x); pk[1]=(short)f2bf(x0.y);
      pk[2]=(short)f2bf(x0.z); pk[3]=(short)f2bf(x0.w);
      pk[4]=(short)f2bf(x1.x); pk[5]=(short)f2bf(x1.y);
      pk[6]=(short)f2bf(x1.z); pk[7]=(short)f2bf(x1.w);
      areg[mf][kt] = pk;
    }
    ss += __shfl_xor(ss, 16, 64);    // lanes l, l^16, l^32, l^48 share a row
    ss += __shfl_xor(ss, 32, 64);
    rs_self[mf] = 1.0f / fmaxf(sqrtf(ss), 1e-12f);
  }
  if (lane < 16){                    // wave-local publish/read: no barrier
    rowinv[w*32 + lane]      = rs_self[0];
    rowinv[w*32 + 16 + lane] = rs_self[1];
  }

  int labreg[2][4];
  float rs[2][4];
#pragma unroll
  for (int m = 0; m < 2; ++m)
#pragma unroll
    for (int j = 0; j < 4; ++j){
      int rr = w*32 + m*16 + g*4 + j;       // C-frag row of acc[m][*][j]
      labreg[m][j] = label[rowbase + rr];
      rs[m][j] = rowinv[rr];
    }

  // ---- staging: wave w owns frags p = w*4+nb (its k-slice k=w, nb=0..3).
  // frag(k,nb) lane l = nmem[ch*64 + nb*16 + r16] bytes [k*64+g*16, +16)
  const char* sbase = (const char*)nmem + (size_t)(r16*512 + w*64 + g*16);
  char* dbase = (char*)Bl + w*4096;

#define STAGE(CH, BUF)                                                        \
  {                                                                           \
    const char* s0 = sbase + (CH)*32768;                                      \
    char* d0 = dbase + (BUF)*32768;                                           \
    _Pragma("unroll")                                                         \
    for (int i = 0; i < 4; ++i){                                              \
      __builtin_amdgcn_global_load_lds(                                       \
        (const __attribute__((address_space(1))) unsigned*)(s0 + i*8192),     \
        (__attribute__((address_space(3))) unsigned*)(d0 + i*1024), 16, 0, 0);\
    }                                                                         \
  }

  STAGE(0, 0);
  asm volatile("s_waitcnt vmcnt(0)" ::: "memory");   // drains A-loads + stage0
  __builtin_amdgcn_s_barrier();

  float esum[2][4] = {{0.f,0.f,0.f,0.f},{0.f,0.f,0.f,0.f}};
  float slb [2][4] = {{0.f,0.f,0.f,0.f},{0.f,0.f,0.f,0.f}};

  for (int ch = 0; ch < 16; ++ch){
    if (ch < 15) STAGE(ch+1, (ch+1)&1);     // in flight across the compute

    const char* bp = (const char*)Bl + (ch&1)*32768 + lane*16;
    f32x4 acc[2][4];
#pragma unroll
    for (int m = 0; m < 2; ++m)
#pragma unroll
      for (int n = 0; n < 4; ++n){ f32x4 z = {0.f,0.f,0.f,0.f}; acc[m][n] = z; }

#pragma unroll
    for (int k = 0; k < 8; ++k){
      bf16x8 b0 = *(const bf16x8*)(bp + (k*4+0)*1024);
      bf16x8 b1 = *(const bf16x8*)(bp + (k*4+1)*1024);
      bf16x8 b2 = *(const bf16x8*)(bp + (k*4+2)*1024);
      bf16x8 b3 = *(const bf16x8*)(bp + (k*4+3)*1024);
      acc[0][0] = __builtin_amdgcn_mfma_f32_16x16x32_bf16(areg[0][k], b0, acc[0][0], 0, 0, 0);
      acc[0][1] = __builtin_amdgcn_mfma_f32_16x16x32_bf16(areg[0][k], b1, acc[0][1], 0, 0, 0);
      acc[0][2] = __builtin_amdgcn_mfma_f32_16x16x32_bf16(areg[0][k], b2, acc[0][2], 0, 0, 0);
      acc[0][3] = __builtin_amdgcn_mfma_f32_16x16x32_bf16(areg[0][k], b3, acc[0][3], 0, 0, 0);
      acc[1][0] = __builtin_amdgcn_mfma_f32_16x16x32_bf16(areg[1][k], b0, acc[1][0], 0, 0, 0);
      acc[1][1] = __builtin_amdgcn_mfma_f32_16x16x32_bf16(areg[1][k], b1, acc[1][1], 0, 0, 0);
      acc[1][2] = __builtin_amdgcn_mfma_f32_16x16x32_bf16(areg[1][k], b2, acc[1][2], 0, 0, 0);
      acc[1][3] = __builtin_amdgcn_mfma_f32_16x16x32_bf16(areg[1][k], b3, acc[1][3], 0, 0, 0);
    }

    // ---- epilogue: scale by row inv-norm, exp-accumulate, label select
#pragma unroll
    for (int m = 0; m < 2; ++m)
#pragma unroll
      for (int n = 0; n < 4; ++n){
        int col = ch*64 + n*16 + r16;
#pragma unroll
        for (int j = 0; j < 4; ++j){
          float v = acc[m][n][j] * rs[m][j];
          esum[m][j] += __expf(v);
          slb[m][j]  += (col == labreg[m][j]) ? v : 0.f;
        }
      }

    asm volatile("s_waitcnt vmcnt(0)" ::: "memory");  // next buf landed
    __builtin_amdgcn_s_barrier();                     // all waves past reads
  }

  // ---- final: reduce 16-lane groups once, per-block loss partial
  float v = 0.f;
#pragma unroll
  for (int m = 0; m < 2; ++m)
#pragma unroll
    for (int j = 0; j < 4; ++j){
      float e = esum[m][j], s = slb[m][j];
      e += __shfl_xor(e, 1, 64); e += __shfl_xor(e, 2, 64);
      e += __shfl_xor(e, 4, 64); e += __shfl_xor(e, 8, 64);
      s += __shfl_xor(s, 1, 64); s += __shfl_xor(s, 2, 64);
      s += __shfl_xor(s, 4, 64); s += __shfl_xor(s, 8, 64);
      v += __logf(e - 24.0f) - s;      // 24 padded cols contribute exp(0)=1
    }
  if (r16 != 0) v = 0.f;               // one lane per 16-lane row-group
  v = wred(v);
  if (lane == 0) bred[w] = v;
  __syncthreads();
  if (t == 0){
    float s = 0.f;
#pragma unroll
    for (int i = 0; i < 8; ++i) s += bred[i];
    partials[blockIdx.x] = s;
  }
}

// ---------------------------------------------------------------------------
// Kernel 3: reduce 512 block partials -> mean loss (deterministic order)
// ---------------------------------------------------------------------------
__global__ __launch_bounds__(256) void k_final(
    const float* __restrict__ partials, float* __restrict__ out){
  const int t = threadIdx.x;
  const int w = t >> 6, lane = t & 63;
  __shared__ float red[4];
  float s = partials[t] + partials[t+256];
  s = wred(s);
  if (lane == 0) red[w] = s;
  __syncthreads();
  if (t == 0) out[0] = (red[0]+red[1]+red[2]+red[3]) * (1.0f/(float)NROWS);
}

// ---------------------------------------------------------------------------
// ws layout: [0, 524288) new_memory bf16 bits (1024x256), [524288, +2048) partials
// ---------------------------------------------------------------------------
extern "C" void kernel_launch(void* const* d_in, const int* in_sizes, int n_in,
                              void* d_out, int out_size, void* d_ws, size_t ws_size,
                              hipStream_t stream){
  const float* feat   = (const float*)d_in[0];
  const float* memory = (const float*)d_in[1];
  const int*   label  = (const int*)d_in[2];
  float* out = (float*)d_out;
  ushort* nmem = (ushort*)d_ws;
  float* partials = (float*)((char*)d_ws + (size_t)CPAD*DDIM*2);

  k_center<<<CPAD/2, 1024, 0, stream>>>(feat, memory, label, nmem);
  k_gemm<<<NROWS/256, 512, 0, stream>>>(feat, nmem, label, partials);
  k_final<<<1, 256, 0, stream>>>(partials, out);
}